// Round 7
// baseline (124.954 us; speedup 1.0000x reference)
//
#include <hip/hip_runtime.h>

#define BATCH 4096
#define CTX 10
#define NEG 20
#define DIM 128
#define NWORDS (CTX + CTX * NEG)     // 210
#define NOCC (BATCH * NWORDS)        // 860160 occurrences
#define NPOS (BATCH * CTX)           // 40960 positive slots
#define V 50000
#define VPAD 50048                   // padded vocab (multiple of 64)
#define CAP 48                       // max occurrences kept per word (mean 17.2, +7 sigma)

// ---- workspace layout (bytes) ----
#define WS_CUR 0                               // VPAD ints   : per-word cursors
#define WS_ITEMS (VPAD * 4)                    // VPAD*CAP ints: packed (b<<8|slot)
#define WS_IVEC (WS_ITEMS + VPAD * CAP * 4)    // BATCH*DIM floats: compact ivecs
#define WS_PART (WS_IVEC + BATCH * DIM * 4)    // 1024 floats: block partials
#define WS_NEED (WS_PART + 1024 * 4)           // ~11.9 MB

#define NBLK_COMPUTE 782                       // 782*64 groups = 50048 >= V

__device__ __forceinline__ float log_sigmoid(float x) {
    return fminf(x, 0.0f) - __logf(1.0f + __expf(-fabsf(x)));
}

// ---------------- fast path ----------------

// Scatter occurrences into per-word buckets; also compact the 4096 used ivecs.
__global__ __launch_bounds__(256) void sgns_scatter(
    const float* __restrict__ emb_i, const int* __restrict__ iword,
    const int* __restrict__ owords, const int* __restrict__ nwords,
    int* __restrict__ cur, int* __restrict__ items, float* __restrict__ ivec_c)
{
    const int j = blockIdx.x * 256 + threadIdx.x;   // 0 .. NOCC-1

    // side duty: compact ivec table (4096 rows x 32 float4)
    if (j < BATCH * DIM / 4) {
        const int row = j >> 5, frag = j & 31;
        const int iw = iword[row];
        reinterpret_cast<float4*>(ivec_c)[(size_t)row * 32 + frag] =
            reinterpret_cast<const float4*>(emb_i)[(size_t)iw * 32 + frag];
    }

    int w, b, slot;
    if (j < NPOS) {
        w = owords[j];  b = j / CTX;  slot = j % CTX;
    } else {
        const int jj = j - NPOS;
        w = nwords[jj]; b = jj / (CTX * NEG); slot = CTX + jj % (CTX * NEG);
    }
    const int pos = atomicAdd(&cur[w], 1);
    if (pos < CAP)
        items[(size_t)w * CAP + pos] = (b << 8) | slot;
}

// One 4-lane group per WORD: row loaded once into registers, reused across
// all its occurrences; ivec gathers hit the compact 2MB L2-resident buffer.
__global__ __launch_bounds__(256) void sgns_compute(
    const float* __restrict__ emb_o, const float* __restrict__ ivec_c,
    const int* __restrict__ items, const int* __restrict__ cur,
    float* __restrict__ partials)
{
    __shared__ float s_wsum[4];
    const int tid = threadIdx.x;
    const int g   = (blockIdx.x * 256 + tid) >> 2;   // word id
    const int sub = tid & 3;

    float acc = 0.0f;
    if (g < V) {
        const int cnt = min(cur[g], CAP);
        if (cnt > 0) {
            // this word's emb_o row: 8 float4 per lane (coalesced sweep:
            // consecutive groups = consecutive rows)
            const float4* __restrict__ rp =
                reinterpret_cast<const float4*>(emb_o + (size_t)g * DIM) + sub;
            float4 r[8];
            #pragma unroll
            for (int u = 0; u < 8; ++u) r[u] = rp[4 * u];

            const int* __restrict__ it = items + (size_t)g * CAP;
            for (int i = 0; i < cnt; ++i) {
                const int pk   = it[i];          // 4 lanes same addr: broadcast
                const int b    = pk >> 8;
                const int slot = pk & 255;
                const float4* __restrict__ qp =
                    reinterpret_cast<const float4*>(ivec_c + (size_t)b * DIM) + sub;
                float a0 = 0.f, a1 = 0.f, a2 = 0.f, a3 = 0.f;
                #pragma unroll
                for (int u = 0; u < 8; ++u) {
                    const float4 q = qp[4 * u];  // L2-resident compact buffer
                    a0 = fmaf(q.x, r[u].x, a0);
                    a1 = fmaf(q.y, r[u].y, a1);
                    a2 = fmaf(q.z, r[u].z, a2);
                    a3 = fmaf(q.w, r[u].w, a3);
                }
                float pd = (a0 + a1) + (a2 + a3);
                pd += __shfl_xor(pd, 1, 64);
                pd += __shfl_xor(pd, 2, 64);
                const float x = (slot < CTX) ? pd : -pd;
                acc += log_sigmoid(x);           // counted 4x; scaled in reduce
            }
        }
    }

    #pragma unroll
    for (int off = 32; off > 0; off >>= 1)
        acc += __shfl_xor(acc, off, 64);
    if ((tid & 63) == 0) s_wsum[tid >> 6] = acc;
    __syncthreads();
    if (tid == 0)
        partials[blockIdx.x] = s_wsum[0] + s_wsum[1] + s_wsum[2] + s_wsum[3];
}

__global__ __launch_bounds__(256) void sgns_reduce_fast(
    const float* __restrict__ partials, float* __restrict__ out)
{
    __shared__ float s[4];
    const int tid = threadIdx.x;
    float acc = 0.0f;
    for (int i = tid; i < NBLK_COMPUTE; i += 256) acc += partials[i];
    #pragma unroll
    for (int off = 32; off > 0; off >>= 1)
        acc += __shfl_xor(acc, off, 64);
    if ((tid & 63) == 0) s[tid >> 6] = acc;
    __syncthreads();
    if (tid == 0)
        out[0] = -0.25f * (s[0] + s[1] + s[2] + s[3]) / (float)(BATCH * CTX);
}

// ---------------- fallback path (R6, used only if ws too small) ----------------

#define GPR 32
#define NPASS 7

__global__ __launch_bounds__(256) void sgns_partial_fb(
    const float* __restrict__ emb_i, const float* __restrict__ emb_o,
    const int* __restrict__ iword, const int* __restrict__ owords,
    const int* __restrict__ nwords, float* __restrict__ wsum)
{
    const int gtid = blockIdx.x * 256 + threadIdx.x;
    const int G = gtid >> 2, sub = gtid & 3;
    const int b = G >> 5, gl = G & 31;

    const int iw = iword[b];
    const float4* __restrict__ qp =
        reinterpret_cast<const float4*>(emb_i + (size_t)iw * DIM) + sub;
    float4 q[8];
    #pragma unroll
    for (int u = 0; u < 8; ++u) q[u] = qp[4 * u];

    int idx[NPASS];
    #pragma unroll
    for (int p = 0; p < NPASS; ++p) {
        const int j = gl + GPR * p;
        idx[p] = (j >= NWORDS) ? -1
               : (j < CTX)     ? owords[b * CTX + j]
                               : nwords[b * (CTX * NEG) + (j - CTX)];
    }

    float acc = 0.0f;
    #pragma unroll
    for (int p = 0; p < NPASS; ++p) {
        if (idx[p] >= 0) {
            const float4* __restrict__ rp =
                reinterpret_cast<const float4*>(emb_o + (size_t)idx[p] * DIM) + sub;
            float4 r[8];
            #pragma unroll
            for (int u = 0; u < 8; ++u) r[u] = rp[4 * u];
            float a0 = 0.f, a1 = 0.f, a2 = 0.f, a3 = 0.f;
            #pragma unroll
            for (int u = 0; u < 8; ++u) {
                a0 = fmaf(q[u].x, r[u].x, a0);
                a1 = fmaf(q[u].y, r[u].y, a1);
                a2 = fmaf(q[u].z, r[u].z, a2);
                a3 = fmaf(q[u].w, r[u].w, a3);
            }
            float pd = (a0 + a1) + (a2 + a3);
            pd += __shfl_xor(pd, 1, 64);
            pd += __shfl_xor(pd, 2, 64);
            const int j = gl + GPR * p;
            const float x = (j < CTX) ? pd : -pd;
            acc += log_sigmoid(x);
        }
    }
    #pragma unroll
    for (int off = 32; off > 0; off >>= 1)
        acc += __shfl_xor(acc, off, 64);
    if ((threadIdx.x & 63) == 0) wsum[gtid >> 6] = acc;
}

__global__ __launch_bounds__(256) void sgns_reduce_fb(
    const float* __restrict__ wsum, float* __restrict__ out)
{
    __shared__ float s[4];
    const int tid = threadIdx.x;
    float acc = 0.0f;
    #pragma unroll
    for (int k = 0; k < 8; ++k) {
        const float4 v = reinterpret_cast<const float4*>(wsum)[tid + 256 * k];
        acc += (v.x + v.y) + (v.z + v.w);
    }
    #pragma unroll
    for (int off = 32; off > 0; off >>= 1)
        acc += __shfl_xor(acc, off, 64);
    if ((tid & 63) == 0) s[tid >> 6] = acc;
    __syncthreads();
    if (tid == 0)
        out[0] = -0.25f * (s[0] + s[1] + s[2] + s[3]) / (float)(BATCH * CTX);
}

extern "C" void kernel_launch(void* const* d_in, const int* in_sizes, int n_in,
                              void* d_out, int out_size, void* d_ws, size_t ws_size,
                              hipStream_t stream) {
    const float* emb_i  = (const float*)d_in[0];
    const float* emb_o  = (const float*)d_in[1];
    const int*   iword  = (const int*)d_in[2];
    const int*   owords = (const int*)d_in[3];
    const int*   nwords = (const int*)d_in[4];
    float* out = (float*)d_out;
    char*  ws  = (char*)d_ws;

    if (ws_size >= (size_t)WS_NEED) {
        int*   cur      = (int*)(ws + WS_CUR);
        int*   items    = (int*)(ws + WS_ITEMS);
        float* ivec_c   = (float*)(ws + WS_IVEC);
        float* partials = (float*)(ws + WS_PART);

        hipMemsetAsync(cur, 0, VPAD * 4, stream);
        sgns_scatter<<<NOCC / 256, 256, 0, stream>>>(
            emb_i, iword, owords, nwords, cur, items, ivec_c);
        sgns_compute<<<NBLK_COMPUTE, 256, 0, stream>>>(
            emb_o, ivec_c, items, cur, partials);
        sgns_reduce_fast<<<1, 256, 0, stream>>>(partials, out);
    } else {
        float* wsum = (float*)ws;   // 8192 floats = 32 KB
        sgns_partial_fb<<<BATCH * GPR * 4 / 256, 256, 0, stream>>>(
            emb_i, emb_o, iword, owords, nwords, wsum);
        sgns_reduce_fb<<<1, 256, 0, stream>>>(wsum, out);
    }
}

// Round 8
// 61.090 us; speedup vs baseline: 2.0454x; 2.0454x over previous
//
#include <hip/hip_runtime.h>

#define BATCH 4096
#define CTX 10
#define NEG 20
#define DIM 128
#define NWORDS (CTX + CTX * NEG)     // 210
#define NOCC (BATCH * NWORDS)        // 860160
#define NPOS (BATCH * CTX)           // 40960
#define NSLICE 8
#define STRIP 256                    // occurrences filtered per wave
#define NSTRIP (NOCC / STRIP)        // 3360 (exact)
#define WPB 4                        // waves per block
#define NBLK (NSTRIP / WPB * NSLICE) // 840 * 8 = 6720

// ---- workspace layout (bytes) ----
#define WS_IVEC 0                          // BATCH*DIM floats = 2 MB
#define WS_PART (BATCH * DIM * 4)          // NBLK floats
#define WS_NEED (WS_PART + NBLK * 4)

__device__ __forceinline__ float log_sigmoid(float x) {
    return fminf(x, 0.0f) - __logf(1.0f + __expf(-fabsf(x)));
}

// compact the 4096 used ivecs into a dense 2MB (L2-resident) buffer
__global__ __launch_bounds__(256) void sgns_ivec(
    const float* __restrict__ emb_i, const int* __restrict__ iword,
    float* __restrict__ ivec_c)
{
    const int k = blockIdx.x * 256 + threadIdx.x;   // 0 .. BATCH*32-1
    const int row = k >> 5, frag = k & 31;
    const int iw = iword[row];
    reinterpret_cast<float4*>(ivec_c)[(size_t)row * 32 + frag] =
        reinterpret_cast<const float4*>(emb_i)[(size_t)iw * 32 + frag];
}

// Slice-filtered main kernel. slice = blockIdx&7 (pinned to one XCD by the
// round-robin block->XCD mapping): each XCD touches only words w&7==slice
// (3.2 MB of emb_o, L2-resident) + the 2MB ivec_c buffer. Wave-private LDS
// queue via ballot-compaction: no atomics, deterministic.
__global__ __launch_bounds__(256) void sgns_main(
    const float* __restrict__ emb_o, const float* __restrict__ ivec_c,
    const int* __restrict__ owords, const int* __restrict__ nwords,
    float* __restrict__ partials)
{
    __shared__ int   q[WPB * STRIP];
    __shared__ float s_wsum[WPB];

    const int tid   = threadIdx.x;
    const int wave  = tid >> 6;
    const int lane  = tid & 63;
    const int slice = blockIdx.x & 7;
    const int strip = (blockIdx.x >> 3) * WPB + wave;
    const int base  = strip * STRIP;
    int* __restrict__ wq = q + wave * STRIP;

    const unsigned long long lt = (1ull << lane) - 1;
    int qn = 0;
    #pragma unroll
    for (int h = 0; h < STRIP / 64; ++h) {
        const int j = base + h * 64 + lane;     // coalesced index read
        int w, b, ispos;
        if (j < NPOS) { w = owords[j];           b = j / CTX;              ispos = 1; }
        else { const int jj = j - NPOS; w = nwords[jj]; b = jj / (CTX * NEG); ispos = 0; }
        const bool keep = ((w & 7) == slice);
        const unsigned long long m = __ballot(keep);
        if (keep)
            wq[qn + __popcll(m & lt)] = (w << 13) | (b << 1) | ispos;
        qn += __popcll(m);                       // wave-uniform
    }
    __syncthreads();   // queue visible (uniform control flow across waves)

    const int g   = lane >> 2;     // 16 groups of 4 lanes per wave
    const int sub = lane & 3;
    float acc = 0.0f;
    for (int i = g; i < qn; i += 16) {
        const int pk = wq[i];                    // 4 lanes same addr: broadcast
        const int w  = pk >> 13;
        const int b  = (pk >> 1) & 0xFFF;
        const float4* __restrict__ rp =
            reinterpret_cast<const float4*>(emb_o + (size_t)w * DIM) + sub;
        const float4* __restrict__ qp =
            reinterpret_cast<const float4*>(ivec_c + (size_t)b * DIM) + sub;
        float4 r[8], qv[8];
        #pragma unroll
        for (int u = 0; u < 8; ++u) r[u] = rp[4 * u];
        #pragma unroll
        for (int u = 0; u < 8; ++u) qv[u] = qp[4 * u];
        float a0 = 0.f, a1 = 0.f, a2 = 0.f, a3 = 0.f;
        #pragma unroll
        for (int u = 0; u < 8; ++u) {
            a0 = fmaf(qv[u].x, r[u].x, a0);
            a1 = fmaf(qv[u].y, r[u].y, a1);
            a2 = fmaf(qv[u].z, r[u].z, a2);
            a3 = fmaf(qv[u].w, r[u].w, a3);
        }
        float pd = (a0 + a1) + (a2 + a3);
        pd += __shfl_xor(pd, 1, 64);
        pd += __shfl_xor(pd, 2, 64);
        const float x = (pk & 1) ? pd : -pd;     // negatives: log_sigmoid(-dot)
        acc += log_sigmoid(x);                   // counted 4x; scaled in reduce
    }

    #pragma unroll
    for (int off = 32; off > 0; off >>= 1)
        acc += __shfl_xor(acc, off, 64);
    if (lane == 0) s_wsum[wave] = acc;
    __syncthreads();
    if (tid == 0)
        partials[blockIdx.x] = s_wsum[0] + s_wsum[1] + s_wsum[2] + s_wsum[3];
}

__global__ __launch_bounds__(256) void sgns_reduce(
    const float* __restrict__ partials, float* __restrict__ out)
{
    __shared__ float s[4];
    const int tid = threadIdx.x;
    float acc = 0.0f;
    for (int i = tid; i < NBLK; i += 256) acc += partials[i];
    #pragma unroll
    for (int off = 32; off > 0; off >>= 1)
        acc += __shfl_xor(acc, off, 64);
    if ((tid & 63) == 0) s[tid >> 6] = acc;
    __syncthreads();
    if (tid == 0)
        out[0] = -0.25f * (s[0] + s[1] + s[2] + s[3]) / (float)(BATCH * CTX);
}

// ---------------- fallback (R6) if ws too small ----------------
#define GPR 32
#define NPASS 7

__global__ __launch_bounds__(256) void sgns_partial_fb(
    const float* __restrict__ emb_i, const float* __restrict__ emb_o,
    const int* __restrict__ iword, const int* __restrict__ owords,
    const int* __restrict__ nwords, float* __restrict__ wsum)
{
    const int gtid = blockIdx.x * 256 + threadIdx.x;
    const int G = gtid >> 2, sub = gtid & 3;
    const int b = G >> 5, gl = G & 31;
    const int iw = iword[b];
    const float4* __restrict__ qp =
        reinterpret_cast<const float4*>(emb_i + (size_t)iw * DIM) + sub;
    float4 q[8];
    #pragma unroll
    for (int u = 0; u < 8; ++u) q[u] = qp[4 * u];
    int idx[NPASS];
    #pragma unroll
    for (int p = 0; p < NPASS; ++p) {
        const int j = gl + GPR * p;
        idx[p] = (j >= NWORDS) ? -1
               : (j < CTX)     ? owords[b * CTX + j]
                               : nwords[b * (CTX * NEG) + (j - CTX)];
    }
    float acc = 0.0f;
    #pragma unroll
    for (int p = 0; p < NPASS; ++p) {
        if (idx[p] >= 0) {
            const float4* __restrict__ rp =
                reinterpret_cast<const float4*>(emb_o + (size_t)idx[p] * DIM) + sub;
            float4 r[8];
            #pragma unroll
            for (int u = 0; u < 8; ++u) r[u] = rp[4 * u];
            float a0 = 0.f, a1 = 0.f, a2 = 0.f, a3 = 0.f;
            #pragma unroll
            for (int u = 0; u < 8; ++u) {
                a0 = fmaf(q[u].x, r[u].x, a0);
                a1 = fmaf(q[u].y, r[u].y, a1);
                a2 = fmaf(q[u].z, r[u].z, a2);
                a3 = fmaf(q[u].w, r[u].w, a3);
            }
            float pd = (a0 + a1) + (a2 + a3);
            pd += __shfl_xor(pd, 1, 64);
            pd += __shfl_xor(pd, 2, 64);
            const int j = gl + GPR * p;
            acc += log_sigmoid((j < CTX) ? pd : -pd);
        }
    }
    #pragma unroll
    for (int off = 32; off > 0; off >>= 1)
        acc += __shfl_xor(acc, off, 64);
    if ((threadIdx.x & 63) == 0) wsum[gtid >> 6] = acc;
}

__global__ __launch_bounds__(256) void sgns_reduce_fb(
    const float* __restrict__ wsum, float* __restrict__ out)
{
    __shared__ float s[4];
    const int tid = threadIdx.x;
    float acc = 0.0f;
    #pragma unroll
    for (int k = 0; k < 8; ++k) {
        const float4 v = reinterpret_cast<const float4*>(wsum)[tid + 256 * k];
        acc += (v.x + v.y) + (v.z + v.w);
    }
    #pragma unroll
    for (int off = 32; off > 0; off >>= 1)
        acc += __shfl_xor(acc, off, 64);
    if ((tid & 63) == 0) s[tid >> 6] = acc;
    __syncthreads();
    if (tid == 0)
        out[0] = -0.25f * (s[0] + s[1] + s[2] + s[3]) / (float)(BATCH * CTX);
}

extern "C" void kernel_launch(void* const* d_in, const int* in_sizes, int n_in,
                              void* d_out, int out_size, void* d_ws, size_t ws_size,
                              hipStream_t stream) {
    const float* emb_i  = (const float*)d_in[0];
    const float* emb_o  = (const float*)d_in[1];
    const int*   iword  = (const int*)d_in[2];
    const int*   owords = (const int*)d_in[3];
    const int*   nwords = (const int*)d_in[4];
    float* out = (float*)d_out;
    char*  ws  = (char*)d_ws;

    if (ws_size >= (size_t)WS_NEED) {
        float* ivec_c   = (float*)(ws + WS_IVEC);
        float* partials = (float*)(ws + WS_PART);
        sgns_ivec<<<BATCH * 32 / 256, 256, 0, stream>>>(emb_i, iword, ivec_c);
        sgns_main<<<NBLK, 256, 0, stream>>>(emb_o, ivec_c, owords, nwords, partials);
        sgns_reduce<<<1, 256, 0, stream>>>(partials, out);
    } else {
        float* wsum = (float*)ws;
        sgns_partial_fb<<<BATCH * GPR * 4 / 256, 256, 0, stream>>>(
            emb_i, emb_o, iword, owords, nwords, wsum);
        sgns_reduce_fb<<<1, 256, 0, stream>>>(wsum, out);
    }
}

// Round 9
// 51.976 us; speedup vs baseline: 2.4041x; 1.1754x over previous
//
#include <hip/hip_runtime.h>

#define BATCH 4096
#define CTX 10
#define NEG 20
#define DIM 128
#define NPOS (BATCH * CTX)                  // 40960 positive items
#define NNEG (BATCH * CTX * NEG)            // 819200 negative items
#define BSTRIP 1024                         // negative occurrences per block
#define NNEGBLK (NNEG / BSTRIP * 8)         // 800 * 8 slices = 6400
#define NPOSBLK (NPOS / 64)                 // 640
#define NPART (NNEGBLK + NPOSBLK)           // 7040
#define IVROWS 8                            // >= max distinct ivec rows/block (7)
#define IVSTRIDE 136                        // padded row stride (floats): +8 banks/row

__device__ __forceinline__ float log_sigmoid(float x) {
    return fminf(x, 0.0f) - __logf(1.0f + __expf(-fabsf(x)));
}

// Negatives: block = (strip of 1024 consecutive nwords occurrences) x (slice).
// slice = blockIdx&7 -> pinned to one XCD (emb_o slice L2-resident, proven R8).
// The strip's batch rows are CONTIGUOUS (b = j/200, <=7 rows) -> ivec staged in
// LDS once; inner loop touches only 8 global lines per item (emb_o row).
__global__ __launch_bounds__(256) void sgns_neg(
    const float* __restrict__ emb_i, const float* __restrict__ emb_o,
    const int* __restrict__ iword, const int* __restrict__ nwords,
    float* __restrict__ partials)
{
    __shared__ float s_ivec[IVROWS * IVSTRIDE];
    __shared__ int   wq[4 * 256];
    __shared__ float s_wsum[4];

    const int tid   = threadIdx.x;
    const int wave  = tid >> 6;
    const int lane  = tid & 63;
    const int slice = blockIdx.x & 7;
    const int base  = (blockIdx.x >> 3) * BSTRIP;
    const int b_lo  = base / 200;
    const int nrows = (base + BSTRIP - 1) / 200 - b_lo + 1;   // <= 7

    // stage this block's ivec rows (each row: 32 float4, coalesced)
    for (int k = tid; k < nrows * 32; k += 256) {
        const int r = k >> 5, f = k & 31;
        const int iw = iword[b_lo + r];
        *reinterpret_cast<float4*>(&s_ivec[r * IVSTRIDE + f * 4]) =
            *reinterpret_cast<const float4*>(emb_i + (size_t)iw * DIM + 4 * f);
    }

    // ballot-compact this wave's 256 occurrences into its private queue
    int* __restrict__ q = wq + wave * 256;
    const unsigned long long lt = (1ull << lane) - 1;
    int qn = 0;
    #pragma unroll
    for (int h = 0; h < 4; ++h) {
        const int j  = base + wave * 256 + h * 64 + lane;  // coalesced
        const int w  = nwords[j];
        const int bl = j / 200 - b_lo;                     // 0..6
        const bool keep = ((w & 7) == slice);
        const unsigned long long m = __ballot(keep);
        if (keep) q[qn + __popcll(m & lt)] = (w << 3) | bl;
        qn += __popcll(m);                                 // wave-uniform
    }
    __syncthreads();   // s_ivec visible (wq is wave-private)

    // 16 groups of 4 lanes; 2 items in flight per group for MLP
    const int g = lane >> 2, sub = lane & 3;
    float acc = 0.0f;
    for (int i = g; i < qn; i += 32) {
        const int  i1   = i + 16;
        const bool has1 = (i1 < qn);
        const int  pk0  = q[i];
        const int  pk1  = q[has1 ? i1 : i];
        const float4* __restrict__ rp0 =
            reinterpret_cast<const float4*>(emb_o + (size_t)(pk0 >> 3) * DIM) + sub;
        const float4* __restrict__ rp1 =
            reinterpret_cast<const float4*>(emb_o + (size_t)(pk1 >> 3) * DIM) + sub;
        float4 r0[8], r1[8];
        #pragma unroll
        for (int u = 0; u < 8; ++u) { r0[u] = rp0[4 * u]; r1[u] = rp1[4 * u]; }

        const float* __restrict__ q0 = &s_ivec[(pk0 & 7) * IVSTRIDE + 4 * sub];
        const float* __restrict__ q1 = &s_ivec[(pk1 & 7) * IVSTRIDE + 4 * sub];
        float a0 = 0.f, a1 = 0.f, a2 = 0.f, a3 = 0.f;
        float c0 = 0.f, c1 = 0.f, c2 = 0.f, c3 = 0.f;
        #pragma unroll
        for (int u = 0; u < 8; ++u) {
            const float4 qa = *reinterpret_cast<const float4*>(q0 + 16 * u);
            const float4 qb = *reinterpret_cast<const float4*>(q1 + 16 * u);
            a0 = fmaf(qa.x, r0[u].x, a0);
            a1 = fmaf(qa.y, r0[u].y, a1);
            a2 = fmaf(qa.z, r0[u].z, a2);
            a3 = fmaf(qa.w, r0[u].w, a3);
            c0 = fmaf(qb.x, r1[u].x, c0);
            c1 = fmaf(qb.y, r1[u].y, c1);
            c2 = fmaf(qb.z, r1[u].z, c2);
            c3 = fmaf(qb.w, r1[u].w, c3);
        }
        float pd0 = (a0 + a1) + (a2 + a3);
        float pd1 = (c0 + c1) + (c2 + c3);
        pd0 += __shfl_xor(pd0, 1, 64);  pd0 += __shfl_xor(pd0, 2, 64);
        pd1 += __shfl_xor(pd1, 1, 64);  pd1 += __shfl_xor(pd1, 2, 64);
        acc += log_sigmoid(-pd0);                 // negatives
        if (has1) acc += log_sigmoid(-pd1);
    }

    #pragma unroll
    for (int off = 32; off > 0; off >>= 1)
        acc += __shfl_xor(acc, off, 64);
    if (lane == 0) s_wsum[wave] = acc;
    __syncthreads();
    if (tid == 0)
        partials[blockIdx.x] = s_wsum[0] + s_wsum[1] + s_wsum[2] + s_wsum[3];
}

// Positives: only 40960 items (4.7%) -- simple gather kernel.
__global__ __launch_bounds__(256) void sgns_pos(
    const float* __restrict__ emb_i, const float* __restrict__ emb_o,
    const int* __restrict__ iword, const int* __restrict__ owords,
    float* __restrict__ partials)
{
    __shared__ float s_wsum[4];
    const int tid  = threadIdx.x;
    const int item = (blockIdx.x * 256 + tid) >> 2;   // < NPOS (exact grid)
    const int sub  = tid & 3;
    const int b    = item / 10;
    const int w    = owords[item];                    // 4 lanes same addr
    const int iw   = iword[b];

    const float4* __restrict__ qp =
        reinterpret_cast<const float4*>(emb_i + (size_t)iw * DIM) + sub;
    const float4* __restrict__ rp =
        reinterpret_cast<const float4*>(emb_o + (size_t)w * DIM) + sub;
    float4 r[8], qv[8];
    #pragma unroll
    for (int u = 0; u < 8; ++u) { r[u] = rp[4 * u]; qv[u] = qp[4 * u]; }
    float a0 = 0.f, a1 = 0.f, a2 = 0.f, a3 = 0.f;
    #pragma unroll
    for (int u = 0; u < 8; ++u) {
        a0 = fmaf(qv[u].x, r[u].x, a0);
        a1 = fmaf(qv[u].y, r[u].y, a1);
        a2 = fmaf(qv[u].z, r[u].z, a2);
        a3 = fmaf(qv[u].w, r[u].w, a3);
    }
    float pd = (a0 + a1) + (a2 + a3);
    pd += __shfl_xor(pd, 1, 64);  pd += __shfl_xor(pd, 2, 64);
    float acc = log_sigmoid(pd);                      // positives

    #pragma unroll
    for (int off = 32; off > 0; off >>= 1)
        acc += __shfl_xor(acc, off, 64);
    if ((tid & 63) == 0) s_wsum[tid >> 6] = acc;
    __syncthreads();
    if (tid == 0)
        partials[NNEGBLK + blockIdx.x] = s_wsum[0] + s_wsum[1] + s_wsum[2] + s_wsum[3];
}

__global__ __launch_bounds__(256) void sgns_reduce(
    const float* __restrict__ partials, float* __restrict__ out)
{
    __shared__ float s[4];
    const int tid = threadIdx.x;
    float acc = 0.0f;
    for (int i = tid; i < NPART; i += 256) acc += partials[i];
    #pragma unroll
    for (int off = 32; off > 0; off >>= 1)
        acc += __shfl_xor(acc, off, 64);
    if ((tid & 63) == 0) s[tid >> 6] = acc;
    __syncthreads();
    if (tid == 0)
        out[0] = -0.25f * (s[0] + s[1] + s[2] + s[3]) / (float)(BATCH * CTX);
}

// ---------------- fallback (R6) if ws too small ----------------
#define NWORDS (CTX + CTX * NEG)
#define GPR 32
#define NPASS 7

__global__ __launch_bounds__(256) void sgns_partial_fb(
    const float* __restrict__ emb_i, const float* __restrict__ emb_o,
    const int* __restrict__ iword, const int* __restrict__ owords,
    const int* __restrict__ nwords, float* __restrict__ wsum)
{
    const int gtid = blockIdx.x * 256 + threadIdx.x;
    const int G = gtid >> 2, sub = gtid & 3;
    const int b = G >> 5, gl = G & 31;
    const int iw = iword[b];
    const float4* __restrict__ qp =
        reinterpret_cast<const float4*>(emb_i + (size_t)iw * DIM) + sub;
    float4 q[8];
    #pragma unroll
    for (int u = 0; u < 8; ++u) q[u] = qp[4 * u];
    int idx[NPASS];
    #pragma unroll
    for (int p = 0; p < NPASS; ++p) {
        const int j = gl + GPR * p;
        idx[p] = (j >= NWORDS) ? -1
               : (j < CTX)     ? owords[b * CTX + j]
                               : nwords[b * (CTX * NEG) + (j - CTX)];
    }
    float acc = 0.0f;
    #pragma unroll
    for (int p = 0; p < NPASS; ++p) {
        if (idx[p] >= 0) {
            const float4* __restrict__ rp =
                reinterpret_cast<const float4*>(emb_o + (size_t)idx[p] * DIM) + sub;
            float4 r[8];
            #pragma unroll
            for (int u = 0; u < 8; ++u) r[u] = rp[4 * u];
            float a0 = 0.f, a1 = 0.f, a2 = 0.f, a3 = 0.f;
            #pragma unroll
            for (int u = 0; u < 8; ++u) {
                a0 = fmaf(q[u].x, r[u].x, a0);
                a1 = fmaf(q[u].y, r[u].y, a1);
                a2 = fmaf(q[u].z, r[u].z, a2);
                a3 = fmaf(q[u].w, r[u].w, a3);
            }
            float pd = (a0 + a1) + (a2 + a3);
            pd += __shfl_xor(pd, 1, 64);
            pd += __shfl_xor(pd, 2, 64);
            const int j = gl + GPR * p;
            acc += log_sigmoid((j < CTX) ? pd : -pd);
        }
    }
    #pragma unroll
    for (int off = 32; off > 0; off >>= 1)
        acc += __shfl_xor(acc, off, 64);
    if ((threadIdx.x & 63) == 0) wsum[gtid >> 6] = acc;
}

__global__ __launch_bounds__(256) void sgns_reduce_fb(
    const float* __restrict__ wsum, float* __restrict__ out)
{
    __shared__ float s[4];
    const int tid = threadIdx.x;
    float acc = 0.0f;
    #pragma unroll
    for (int k = 0; k < 8; ++k) {
        const float4 v = reinterpret_cast<const float4*>(wsum)[tid + 256 * k];
        acc += (v.x + v.y) + (v.z + v.w);
    }
    #pragma unroll
    for (int off = 32; off > 0; off >>= 1)
        acc += __shfl_xor(acc, off, 64);
    if ((tid & 63) == 0) s[tid >> 6] = acc;
    __syncthreads();
    if (tid == 0)
        out[0] = -0.25f * (s[0] + s[1] + s[2] + s[3]) / (float)(BATCH * CTX);
}

extern "C" void kernel_launch(void* const* d_in, const int* in_sizes, int n_in,
                              void* d_out, int out_size, void* d_ws, size_t ws_size,
                              hipStream_t stream) {
    const float* emb_i  = (const float*)d_in[0];
    const float* emb_o  = (const float*)d_in[1];
    const int*   iword  = (const int*)d_in[2];
    const int*   owords = (const int*)d_in[3];
    const int*   nwords = (const int*)d_in[4];
    float* out = (float*)d_out;

    if (ws_size >= (size_t)(NPART * 4)) {
        float* partials = (float*)d_ws;
        sgns_neg<<<NNEGBLK, 256, 0, stream>>>(emb_i, emb_o, iword, nwords, partials);
        sgns_pos<<<NPOSBLK, 256, 0, stream>>>(emb_i, emb_o, iword, owords, partials);
        sgns_reduce<<<1, 256, 0, stream>>>(partials, out);
    } else {
        float* wsum = (float*)d_ws;
        sgns_partial_fb<<<BATCH * GPR * 4 / 256, 256, 0, stream>>>(
            emb_i, emb_o, iword, owords, nwords, wsum);
        sgns_reduce_fb<<<1, 256, 0, stream>>>(wsum, out);
    }
}

// Round 10
// 51.580 us; speedup vs baseline: 2.4225x; 1.0077x over previous
//
#include <hip/hip_runtime.h>

#define BATCH 4096
#define CTX 10
#define NEG 20
#define DIM 128
#define NPOS (BATCH * CTX)            // 40960
#define NNEG (BATCH * CTX * NEG)      // 819200
#define WSTRIP 512                    // negative occurrences per wave-task
#define NWSTRIP (NNEG / WSTRIP)       // 1600 (exact)
#define NSLICE 8
#define NWTASK (NWSTRIP * NSLICE)     // 12800 wave partials
#define WPB 4
#define NNEGBLK (NWTASK / WPB)        // 3200 blocks
#define NPOSBLK (NPOS / 64)           // 640 blocks
#define NPART (NWTASK + NPOSBLK)      // 13440 partials
#define IVSTR 136                     // padded ivec row stride (floats)

__device__ __forceinline__ float log_sigmoid(float x) {
    return fminf(x, 0.0f) - __logf(1.0f + __expf(-fabsf(x)));
}

// Negatives. Block = 4 independent wave-tasks; wave-task = (512 consecutive
// nwords occurrences) x (slice = blockIdx&7, pinned to one XCD -> emb_o slice
// L2-resident, proven R8/R9). NO __syncthreads anywhere: ivec rows (<=4,
// since 512 occ span <=4 batch rows) live in wave-private LDS; in-wave
// ds_write->ds_read is ordered by lgkmcnt. Compute: 8 groups of 8 lanes,
// runtime-trip-count loop with cur/nxt double buffer (8 rounds -> 7 in
// steady state; trip count unknown at compile time so the compiler cannot
// flatten/merge the buffers like it did in R4/R5).
__global__ __launch_bounds__(256) void sgns_neg(
    const float* __restrict__ emb_i, const float* __restrict__ emb_o,
    const int* __restrict__ iword, const int* __restrict__ nwords,
    float* __restrict__ partials)
{
    __shared__ float s_ivec[WPB][4 * IVSTR];
    __shared__ int   wq[WPB][WSTRIP];

    const int tid   = threadIdx.x;
    const int wave  = tid >> 6;
    const int lane  = tid & 63;
    const int slice = blockIdx.x & 7;
    const int ws    = (blockIdx.x >> 3) * WPB + wave;   // wave-strip id
    const int wbase = ws * WSTRIP;
    const int b_lo  = wbase / 200;

    // stage this wave's <=4 ivec rows (wave-private; index clamped: rows
    // past the strip's span are never referenced)
    float* __restrict__ siv = s_ivec[wave];
    #pragma unroll
    for (int t = lane; t < 128; t += 64) {
        const int r = t >> 5, f = t & 31;
        const int iw = iword[min(b_lo + r, BATCH - 1)];
        *reinterpret_cast<float4*>(&siv[r * IVSTR + 4 * f]) =
            *reinterpret_cast<const float4*>(emb_i + (size_t)iw * DIM + 4 * f);
    }

    // ballot-compact this wave's 512 occurrences into its private queue
    int* __restrict__ q = wq[wave];
    const unsigned long long lt = (1ull << lane) - 1;
    int qn = 0;
    #pragma unroll
    for (int h = 0; h < 8; ++h) {
        const int j  = wbase + h * 64 + lane;   // coalesced
        const int w  = nwords[j];
        const int bl = j / 200 - b_lo;          // 0..3
        const bool keep = ((w & 7) == slice);
        const unsigned long long m = __ballot(keep);
        if (keep) q[qn + __popcll(m & lt)] = (w << 2) | bl;
        qn += __popcll(m);                      // wave-uniform
    }

    // compute: 8 groups x 8 lanes, 2-deep software pipeline
    const int g = lane >> 3, sub = lane & 7;
    float acc = 0.0f;
    float4 cur[4], nxt[4];
    int i = g;
    if (i < qn) {
        const float4* __restrict__ rp =
            reinterpret_cast<const float4*>(emb_o + (size_t)(q[i] >> 2) * DIM) + sub;
        #pragma unroll
        for (int u = 0; u < 4; ++u) cur[u] = rp[8 * u];
    }
    for (; i < qn; i += 8) {
        const int pk = q[i];
        const int in2 = i + 8;
        if (in2 < qn) {
            const float4* __restrict__ rp =
                reinterpret_cast<const float4*>(emb_o + (size_t)(q[in2] >> 2) * DIM) + sub;
            #pragma unroll
            for (int u = 0; u < 4; ++u) nxt[u] = rp[8 * u];
        }
        __builtin_amdgcn_sched_barrier(0);   // prefetch issues before compute

        const float* __restrict__ qp = &siv[(pk & 3) * IVSTR + 4 * sub];
        float a0 = 0.f, a1 = 0.f, a2 = 0.f, a3 = 0.f;
        #pragma unroll
        for (int u = 0; u < 4; ++u) {
            const float4 qv = *reinterpret_cast<const float4*>(qp + 32 * u);
            a0 = fmaf(qv.x, cur[u].x, a0);
            a1 = fmaf(qv.y, cur[u].y, a1);
            a2 = fmaf(qv.z, cur[u].z, a2);
            a3 = fmaf(qv.w, cur[u].w, a3);
        }
        float pd = (a0 + a1) + (a2 + a3);
        pd += __shfl_xor(pd, 1, 64);
        pd += __shfl_xor(pd, 2, 64);
        pd += __shfl_xor(pd, 4, 64);
        acc += log_sigmoid(-pd);             // counted 8x; scaled at write

        #pragma unroll
        for (int u = 0; u < 4; ++u) cur[u] = nxt[u];
    }

    // wave reduce; lane 0 posts the wave partial (no block combine -> no barrier)
    #pragma unroll
    for (int off = 32; off > 0; off >>= 1)
        acc += __shfl_xor(acc, off, 64);
    if (lane == 0)
        partials[blockIdx.x * WPB + wave] = 0.125f * acc;
}

// Positives: 40960 items (4.7%) -- simple gather kernel, 4-lane groups.
__global__ __launch_bounds__(256) void sgns_pos(
    const float* __restrict__ emb_i, const float* __restrict__ emb_o,
    const int* __restrict__ iword, const int* __restrict__ owords,
    float* __restrict__ partials)
{
    __shared__ float s_wsum[4];
    const int tid  = threadIdx.x;
    const int item = (blockIdx.x * 256 + tid) >> 2;
    const int sub  = tid & 3;
    const int b    = item / 10;
    const int w    = owords[item];
    const int iw   = iword[b];

    const float4* __restrict__ qp =
        reinterpret_cast<const float4*>(emb_i + (size_t)iw * DIM) + sub;
    const float4* __restrict__ rp =
        reinterpret_cast<const float4*>(emb_o + (size_t)w * DIM) + sub;
    float4 r[8], qv[8];
    #pragma unroll
    for (int u = 0; u < 8; ++u) { r[u] = rp[4 * u]; qv[u] = qp[4 * u]; }
    float a0 = 0.f, a1 = 0.f, a2 = 0.f, a3 = 0.f;
    #pragma unroll
    for (int u = 0; u < 8; ++u) {
        a0 = fmaf(qv[u].x, r[u].x, a0);
        a1 = fmaf(qv[u].y, r[u].y, a1);
        a2 = fmaf(qv[u].z, r[u].z, a2);
        a3 = fmaf(qv[u].w, r[u].w, a3);
    }
    float pd = (a0 + a1) + (a2 + a3);
    pd += __shfl_xor(pd, 1, 64);  pd += __shfl_xor(pd, 2, 64);
    float acc = log_sigmoid(pd);

    #pragma unroll
    for (int off = 32; off > 0; off >>= 1)
        acc += __shfl_xor(acc, off, 64);
    if ((tid & 63) == 0) s_wsum[tid >> 6] = acc;
    __syncthreads();
    if (tid == 0)
        partials[NWTASK + blockIdx.x] =
            0.25f * (s_wsum[0] + s_wsum[1] + s_wsum[2] + s_wsum[3]);
}

__global__ __launch_bounds__(256) void sgns_reduce(
    const float* __restrict__ partials, float* __restrict__ out)
{
    __shared__ float s[4];
    const int tid = threadIdx.x;
    float acc = 0.0f;
    for (int i = tid; i < NPART; i += 256) acc += partials[i];
    #pragma unroll
    for (int off = 32; off > 0; off >>= 1)
        acc += __shfl_xor(acc, off, 64);
    if ((tid & 63) == 0) s[tid >> 6] = acc;
    __syncthreads();
    if (tid == 0)
        out[0] = -(s[0] + s[1] + s[2] + s[3]) / (float)(BATCH * CTX);
}

// ---------------- fallback (R6) if ws too small ----------------
#define NWORDS (CTX + CTX * NEG)
#define GPR 32
#define NPASS 7

__global__ __launch_bounds__(256) void sgns_partial_fb(
    const float* __restrict__ emb_i, const float* __restrict__ emb_o,
    const int* __restrict__ iword, const int* __restrict__ owords,
    const int* __restrict__ nwords, float* __restrict__ wsum)
{
    const int gtid = blockIdx.x * 256 + threadIdx.x;
    const int G = gtid >> 2, sub = gtid & 3;
    const int b = G >> 5, gl = G & 31;
    const int iw = iword[b];
    const float4* __restrict__ qp =
        reinterpret_cast<const float4*>(emb_i + (size_t)iw * DIM) + sub;
    float4 q[8];
    #pragma unroll
    for (int u = 0; u < 8; ++u) q[u] = qp[4 * u];
    int idx[NPASS];
    #pragma unroll
    for (int p = 0; p < NPASS; ++p) {
        const int j = gl + GPR * p;
        idx[p] = (j >= NWORDS) ? -1
               : (j < CTX)     ? owords[b * CTX + j]
                               : nwords[b * (CTX * NEG) + (j - CTX)];
    }
    float acc = 0.0f;
    #pragma unroll
    for (int p = 0; p < NPASS; ++p) {
        if (idx[p] >= 0) {
            const float4* __restrict__ rp =
                reinterpret_cast<const float4*>(emb_o + (size_t)idx[p] * DIM) + sub;
            float4 r[8];
            #pragma unroll
            for (int u = 0; u < 8; ++u) r[u] = rp[4 * u];
            float a0 = 0.f, a1 = 0.f, a2 = 0.f, a3 = 0.f;
            #pragma unroll
            for (int u = 0; u < 8; ++u) {
                a0 = fmaf(q[u].x, r[u].x, a0);
                a1 = fmaf(q[u].y, r[u].y, a1);
                a2 = fmaf(q[u].z, r[u].z, a2);
                a3 = fmaf(q[u].w, r[u].w, a3);
            }
            float pd = (a0 + a1) + (a2 + a3);
            pd += __shfl_xor(pd, 1, 64);
            pd += __shfl_xor(pd, 2, 64);
            const int j = gl + GPR * p;
            acc += log_sigmoid((j < CTX) ? pd : -pd);
        }
    }
    #pragma unroll
    for (int off = 32; off > 0; off >>= 1)
        acc += __shfl_xor(acc, off, 64);
    if ((threadIdx.x & 63) == 0) wsum[gtid >> 6] = acc;
}

__global__ __launch_bounds__(256) void sgns_reduce_fb(
    const float* __restrict__ wsum, float* __restrict__ out)
{
    __shared__ float s[4];
    const int tid = threadIdx.x;
    float acc = 0.0f;
    #pragma unroll
    for (int k = 0; k < 8; ++k) {
        const float4 v = reinterpret_cast<const float4*>(wsum)[tid + 256 * k];
        acc += (v.x + v.y) + (v.z + v.w);
    }
    #pragma unroll
    for (int off = 32; off > 0; off >>= 1)
        acc += __shfl_xor(acc, off, 64);
    if ((tid & 63) == 0) s[tid >> 6] = acc;
    __syncthreads();
    if (tid == 0)
        out[0] = -0.25f * (s[0] + s[1] + s[2] + s[3]) / (float)(BATCH * CTX);
}

extern "C" void kernel_launch(void* const* d_in, const int* in_sizes, int n_in,
                              void* d_out, int out_size, void* d_ws, size_t ws_size,
                              hipStream_t stream) {
    const float* emb_i  = (const float*)d_in[0];
    const float* emb_o  = (const float*)d_in[1];
    const int*   iword  = (const int*)d_in[2];
    const int*   owords = (const int*)d_in[3];
    const int*   nwords = (const int*)d_in[4];
    float* out = (float*)d_out;

    if (ws_size >= (size_t)(NPART * 4)) {
        float* partials = (float*)d_ws;
        sgns_neg<<<NNEGBLK, 256, 0, stream>>>(emb_i, emb_o, iword, nwords, partials);
        sgns_pos<<<NPOSBLK, 256, 0, stream>>>(emb_i, emb_o, iword, owords, partials);
        sgns_reduce<<<1, 256, 0, stream>>>(partials, out);
    } else {
        float* wsum = (float*)d_ws;
        sgns_partial_fb<<<BATCH * GPR * 4 / 256, 256, 0, stream>>>(
            emb_i, emb_o, iword, owords, nwords, wsum);
        sgns_reduce_fb<<<1, 256, 0, stream>>>(wsum, out);
    }
}